// Round 8
// baseline (470.950 us; speedup 1.0000x reference)
//
#include <hip/hip_runtime.h>

// DepthFlowProjectionModule — B=4, H=1080, W=1920, fp32.
// Round 8 = Round 7 resubmit (container unresponsive; no result obtained).
//  - splat_box: Round-6 proven near path (3 LDS atomics/pixel, 2x2 box
//    identity); far tail (~0.55% of pixels) appends ONE compact record to a
//    global list (1 atomic + 16B store) instead of 12 scattered atomics.
//    Flush goes to 3 ws planes (cnt,sx,sy) — plain exclusive stores.
//  - scatter_far: expands ~45K records to 4 corners with global atomics.
//  - norm_fill: single fused pass; reads stable ws planes, normalizes,
//    fills holes (neighbors normalized on the fly: sx[q]/cnt[q]), writes
//    final d_out. No overflow planes, no 100MB memset, no separate norm.

#define TW 80
#define TH 60
#define AW 81             // A-plane cols  (x0-1 .. x0+TW-1)
#define AH 61             // A-plane rows  (y0-1 .. y0+TH-1)
#define APIX (AW * AH)    // 4941 floats/plane; 3 planes = 59292 B LDS
#define EW 128            // read region: gx in [x0-24, x0+103]
#define EH 112            // read region: gy in [y0-26, y0+85]; EW*EH = 14*1024
#define RX 24
#define RY 26
#define DXLO (-24)
#define DXHI 23
#define DYLO (-26)
#define DYHI 25
#define BLK 1024

__global__ __launch_bounds__(BLK, 2) void splat_box(
    const float* __restrict__ flow, const float* __restrict__ depth,
    float* __restrict__ cnt_all, float* __restrict__ sx_all,
    float* __restrict__ sy_all,
    unsigned* __restrict__ counter, float4* __restrict__ list, int cap,
    int B, int H, int W)
{
    __shared__ float lds[3 * APIX];
    float* lc = lds;
    float* lx = lds + APIX;
    float* ly = lds + 2 * APIX;

    int tid = threadIdx.x;
    for (int q = tid; q < 3 * APIX; q += BLK) lds[q] = 0.0f;
    __syncthreads();

    int x0 = blockIdx.x * TW;
    int y0 = blockIdx.y * TH;
    int b  = blockIdx.z;
    int HWp = H * W;
    const float* fb = flow + (size_t)b * 2 * HWp;
    const float* db = depth + (size_t)b * HWp;
    float* cm  = cnt_all + (size_t)b * HWp;
    float* sxm = sx_all + (size_t)b * HWp;
    float* sym = sy_all + (size_t)b * HWp;

    #pragma unroll
    for (int k = 0; k < (EW * EH) / BLK; ++k) {   // 14 exact iterations
        int q = tid + k * BLK;
        int ex = q & (EW - 1);
        int ey = q >> 7;
        int gx = x0 - RX + ex;
        int gy = y0 - RY + ey;
        if ((unsigned)gx >= (unsigned)W || (unsigned)gy >= (unsigned)H) continue;
        int p = gy * W + gx;
        float fx = fb[p], fy = fb[HWp + p];
        float x2 = (float)gx + fx;
        float y2 = (float)gy + fy;
        if (!(x2 >= 0.0f && y2 >= 0.0f && x2 <= (float)(W - 1) && y2 <= (float)(H - 1)))
            continue;
        float w = db[p];
        int ixL = min((int)x2, W - 1);   // x2>=0 -> trunc == floor == jnp astype+clip
        int iyT = min((int)y2, H - 1);
        int dx = ixL - gx;
        int dy = iyT - gy;
        bool near = (dx >= DXLO) & (dx <= DXHI) & (dy >= DYLO) & (dy <= DYHI);
        float vc = w, vx = -fx * w, vy = -fy * w;
        if (near) {
            int ax = ixL - (x0 - 1);
            int ay = iyT - (y0 - 1);
            if ((unsigned)ax < (unsigned)AW && (unsigned)ay < (unsigned)AH) {
                float m = ((ixL == W - 1) ? 2.0f : 1.0f) *
                          ((iyT == H - 1) ? 2.0f : 1.0f);
                int l = ay * AW + ax;
                atomicAdd(&lc[l], vc * m);
                atomicAdd(&lx[l], vx * m);
                atomicAdd(&ly[l], vy * m);
            }
        } else if (((unsigned)(gx - x0) < (unsigned)TW) &&
                   ((unsigned)(gy - y0) < (unsigned)TH)) {
            // far tail: append compact record (expanded by scatter_far)
            unsigned key = (unsigned)ixL | ((unsigned)iyT << 11) | ((unsigned)b << 22);
            unsigned idx = atomicAdd(counter, 1u);
            if (idx < (unsigned)cap)   // 44x headroom vs expected count
                list[idx] = make_float4(__uint_as_float(key), vc, vx, vy);
        }
    }
    __syncthreads();

    // flush: 2x2 box-sum of A, plain exclusive coalesced store to ws planes
    for (int q = tid; q < TW * TH; q += BLK) {
        int oyy = q / TW;
        int oxx = q - oyy * TW;
        int base = (oyy + 1) * AW + (oxx + 1);
        float c  = lc[base] + lc[base - 1] + lc[base - AW] + lc[base - AW - 1];
        float sx = lx[base] + lx[base - 1] + lx[base - AW] + lx[base - AW - 1];
        float sy = ly[base] + ly[base - 1] + ly[base - AW] + ly[base - AW - 1];
        int g = (y0 + oyy) * W + x0 + oxx;
        cm[g]  = c;
        sxm[g] = sx;
        sym[g] = sy;
    }
}

__global__ void scatter_far(const float4* __restrict__ list,
                            const unsigned* __restrict__ counter, int cap,
                            float* __restrict__ cnt_all, float* __restrict__ sx_all,
                            float* __restrict__ sy_all, int HWp, int W, int H)
{
    unsigned n = min(counter[0], (unsigned)cap);
    for (unsigned i = blockIdx.x * blockDim.x + threadIdx.x; i < n;
         i += gridDim.x * blockDim.x) {
        float4 e = list[i];
        unsigned key = __float_as_uint(e.x);
        int x = key & 2047u;
        int y = (key >> 11) & 2047u;
        int b = key >> 22;
        int ixR = min(x + 1, W - 1);
        int iyB = min(y + 1, H - 1);
        size_t base = (size_t)b * HWp;
        int i00 = y * W + x,   i01 = y * W + ixR;
        int i10 = iyB * W + x, i11 = iyB * W + ixR;
        atomicAdd(&cnt_all[base + i00], e.y);
        atomicAdd(&cnt_all[base + i01], e.y);
        atomicAdd(&cnt_all[base + i10], e.y);
        atomicAdd(&cnt_all[base + i11], e.y);
        atomicAdd(&sx_all[base + i00], e.z);
        atomicAdd(&sx_all[base + i01], e.z);
        atomicAdd(&sx_all[base + i10], e.z);
        atomicAdd(&sx_all[base + i11], e.z);
        atomicAdd(&sy_all[base + i00], e.w);
        atomicAdd(&sy_all[base + i01], e.w);
        atomicAdd(&sy_all[base + i10], e.w);
        atomicAdd(&sy_all[base + i11], e.w);
    }
}

// fused normalize + hole-fill: reads stable ws planes, writes final d_out
__global__ void norm_fill(const float* __restrict__ cnt_all,
                          const float* __restrict__ sx_all,
                          const float* __restrict__ sy_all,
                          float* __restrict__ out,
                          int B, int H, int W)
{
    int i = blockIdx.x * blockDim.x + threadIdx.x;
    int HWp = H * W;
    if (i >= B * HWp) return;
    int b = i / HWp;
    int r = i - b * HWp;
    float c = cnt_all[i];
    float rx, ry;
    if (c > 0.0f) {
        rx = sx_all[i] / c;
        ry = sy_all[i] / c;
    } else {
        int y = r / W;
        int x = r - y * W;
        const float* cb  = cnt_all + (size_t)b * HWp;
        const float* sxb = sx_all + (size_t)b * HWp;
        const float* syb = sy_all + (size_t)b * HWp;
        float nx = 0.0f, ny = 0.0f;
        int den = 0;
        for (int xx = x - 1; xx >= 0; --xx) {
            int q = y * W + xx; float cq = cb[q];
            if (cq > 0.0f) { nx += sxb[q] / cq; ny += syb[q] / cq; ++den; break; }
        }
        for (int xx = x + 1; xx < W; ++xx) {
            int q = y * W + xx; float cq = cb[q];
            if (cq > 0.0f) { nx += sxb[q] / cq; ny += syb[q] / cq; ++den; break; }
        }
        for (int yy = y - 1; yy >= 0; --yy) {
            int q = yy * W + x; float cq = cb[q];
            if (cq > 0.0f) { nx += sxb[q] / cq; ny += syb[q] / cq; ++den; break; }
        }
        for (int yy = y + 1; yy < H; ++yy) {
            int q = yy * W + x; float cq = cb[q];
            if (cq > 0.0f) { nx += sxb[q] / cq; ny += syb[q] / cq; ++den; break; }
        }
        if (den > 0) { float fd = (float)den; rx = nx / fd; ry = ny / fd; }
        else         { rx = 0.0f; ry = 0.0f; }   // ref: hole & den==0 keeps 0
    }
    float* ob = out + (size_t)b * 2 * HWp;
    ob[r] = rx;
    ob[HWp + r] = ry;
}

// fallback (ws too small / shape mismatch): global atomics into ws planes
__global__ void splat_naive_ws(const float* __restrict__ flow,
                               const float* __restrict__ depth,
                               float* __restrict__ cnt_all,
                               float* __restrict__ sx_all,
                               float* __restrict__ sy_all,
                               int B, int H, int W)
{
    int i = blockIdx.x * blockDim.x + threadIdx.x;
    int HWp = H * W;
    if (i >= B * HWp) return;
    int b = i / HWp;
    int p = i - b * HWp;
    int y = p / W;
    int x = p - y * W;
    const float* fb = flow + (size_t)b * 2 * HWp;
    float fx = fb[p], fy = fb[HWp + p];
    float x2 = (float)x + fx, y2 = (float)y + fy;
    if (!(x2 >= 0.0f && y2 >= 0.0f && x2 <= (float)(W - 1) && y2 <= (float)(H - 1)))
        return;
    float w = depth[i];
    int ixL = min((int)x2, W - 1);
    int iyT = min((int)y2, H - 1);
    int ixR = min(ixL + 1, W - 1);
    int iyB = min(iyT + 1, H - 1);
    float ax = -fx * w, ay = -fy * w;
    size_t base = (size_t)b * HWp;
    int idx[4] = {iyT * W + ixL, iyT * W + ixR, iyB * W + ixL, iyB * W + ixR};
    #pragma unroll
    for (int c = 0; c < 4; ++c) {
        atomicAdd(&cnt_all[base + idx[c]], w);
        atomicAdd(&sx_all[base + idx[c]], ax);
        atomicAdd(&sy_all[base + idx[c]], ay);
    }
}

extern "C" void kernel_launch(void* const* d_in, const int* in_sizes, int n_in,
                              void* d_out, int out_size, void* d_ws, size_t ws_size,
                              hipStream_t stream) {
    const float* flow  = (const float*)d_in[0];   // (B,2,H,W)
    const float* depth = (const float*)d_in[1];   // (B,1,H,W)
    float* out = (float*)d_out;                   // (B,2,H,W)

    const int H = 1080, W = 1920;
    const int HWp = H * W;
    const int B = in_sizes[1] / HWp;
    const size_t plane = (size_t)B * HWp;

    // ws layout: [cnt plane][sx plane][sy plane][256B counter][far list]
    float* cnt_all = (float*)d_ws;
    float* sx_all  = cnt_all + plane;
    float* sy_all  = cnt_all + 2 * plane;
    unsigned* counter = (unsigned*)(cnt_all + 3 * plane);
    float4* list = (float4*)((char*)counter + 256);
    size_t head = 3 * plane * sizeof(float) + 256;
    long long cap_ll = (ws_size > head) ? (long long)((ws_size - head) / 16) : 0;
    if (cap_ll > 4000000LL) cap_ll = 4000000LL;
    int cap = (int)cap_ll;

    int blocks = (int)((plane + 255) / 256);
    bool tiled = (cap >= 200000) && (W % TW == 0) && (H % TH == 0);

    if (tiled) {
        hipMemsetAsync(counter, 0, 256, stream);   // only the counter
        dim3 grid(W / TW, H / TH, B);              // 24 x 18 x 4
        splat_box<<<grid, BLK, 0, stream>>>(flow, depth, cnt_all, sx_all, sy_all,
                                            counter, list, cap, B, H, W);
        scatter_far<<<128, 256, 0, stream>>>(list, counter, cap,
                                             cnt_all, sx_all, sy_all, HWp, W, H);
    } else if (ws_size >= 3 * plane * sizeof(float)) {
        hipMemsetAsync(d_ws, 0, 3 * plane * sizeof(float), stream);
        splat_naive_ws<<<blocks, 256, 0, stream>>>(flow, depth,
                                                   cnt_all, sx_all, sy_all,
                                                   B, H, W);
    }
    norm_fill<<<blocks, 256, 0, stream>>>(cnt_all, sx_all, sy_all, out, B, H, W);
}

// Round 9
// 282.800 us; speedup vs baseline: 1.6653x; 1.6653x over previous
//
#include <hip/hip_runtime.h>

// DepthFlowProjectionModule — B=4, H=1080, W=1920, fp32.
// Round 9: fix Round-8's regression. The 45K per-thread returning atomics on
// ONE counter line serialized (~4ns each, +190us, VALUBusy 21->10%). Now far
// records stage in a 256-entry LDS buffer (LDS atomics, per-CU); ONE global
// atomicAdd per block reserves a chunk; coalesced copy-out. Plus float4-
// vectorized norm_fill. Near path unchanged (3 LDS atomics/px, 2x2 box).

#define TW 80
#define TH 60
#define AW 81             // A-plane cols  (x0-1 .. x0+TW-1)
#define AH 61             // A-plane rows  (y0-1 .. y0+TH-1)
#define APIX (AW * AH)    // 4941 floats/plane; 3 planes = 59292 B LDS
#define EW 128            // read region: gx in [x0-24, x0+103]
#define EH 112            // read region: gy in [y0-26, y0+85]; EW*EH = 14*1024
#define RX 24
#define RY 26
#define DXLO (-24)
#define DXHI 23
#define DYLO (-26)
#define DYHI 25
#define BLK 1024
#define FCAP 256          // LDS far-record staging (expected ~26/block)

__global__ __launch_bounds__(BLK, 2) void splat_box(
    const float* __restrict__ flow, const float* __restrict__ depth,
    float* __restrict__ cnt_all, float* __restrict__ sx_all,
    float* __restrict__ sy_all,
    unsigned* __restrict__ counter, float4* __restrict__ list, int cap,
    int B, int H, int W)
{
    __shared__ float lds[3 * APIX];
    __shared__ float4 fstage[FCAP];
    __shared__ unsigned fcnt, fbase;
    float* lc = lds;
    float* lx = lds + APIX;
    float* ly = lds + 2 * APIX;

    int tid = threadIdx.x;
    for (int q = tid; q < 3 * APIX; q += BLK) lds[q] = 0.0f;
    if (tid == 0) fcnt = 0;
    __syncthreads();

    int x0 = blockIdx.x * TW;
    int y0 = blockIdx.y * TH;
    int b  = blockIdx.z;
    int HWp = H * W;
    const float* fb = flow + (size_t)b * 2 * HWp;
    const float* db = depth + (size_t)b * HWp;
    float* cm  = cnt_all + (size_t)b * HWp;
    float* sxm = sx_all + (size_t)b * HWp;
    float* sym = sy_all + (size_t)b * HWp;

    #pragma unroll
    for (int k = 0; k < (EW * EH) / BLK; ++k) {   // 14 exact iterations
        int q = tid + k * BLK;
        int ex = q & (EW - 1);
        int ey = q >> 7;
        int gx = x0 - RX + ex;
        int gy = y0 - RY + ey;
        if ((unsigned)gx >= (unsigned)W || (unsigned)gy >= (unsigned)H) continue;
        int p = gy * W + gx;
        float fx = fb[p], fy = fb[HWp + p];
        float x2 = (float)gx + fx;
        float y2 = (float)gy + fy;
        if (!(x2 >= 0.0f && y2 >= 0.0f && x2 <= (float)(W - 1) && y2 <= (float)(H - 1)))
            continue;
        float w = db[p];
        int ixL = min((int)x2, W - 1);   // x2>=0 -> trunc == floor == jnp astype+clip
        int iyT = min((int)y2, H - 1);
        int dx = ixL - gx;
        int dy = iyT - gy;
        bool near = (dx >= DXLO) & (dx <= DXHI) & (dy >= DYLO) & (dy <= DYHI);
        float vc = w, vx = -fx * w, vy = -fy * w;
        if (near) {
            int ax = ixL - (x0 - 1);
            int ay = iyT - (y0 - 1);
            if ((unsigned)ax < (unsigned)AW && (unsigned)ay < (unsigned)AH) {
                float m = ((ixL == W - 1) ? 2.0f : 1.0f) *
                          ((iyT == H - 1) ? 2.0f : 1.0f);
                int l = ay * AW + ax;
                atomicAdd(&lc[l], vc * m);
                atomicAdd(&lx[l], vx * m);
                atomicAdd(&ly[l], vy * m);
            }
        } else if (((unsigned)(gx - x0) < (unsigned)TW) &&
                   ((unsigned)(gy - y0) < (unsigned)TH)) {
            // far tail: stage in LDS (per-CU atomic); global fallback if full
            unsigned key = (unsigned)ixL | ((unsigned)iyT << 11) | ((unsigned)b << 22);
            float4 rec = make_float4(__uint_as_float(key), vc, vx, vy);
            unsigned li = atomicAdd(&fcnt, 1u);
            if (li < FCAP) {
                fstage[li] = rec;
            } else {
                unsigned gi = atomicAdd(counter, 1u);
                if (gi < (unsigned)cap) list[gi] = rec;
            }
        }
    }
    __syncthreads();

    // reserve one contiguous chunk for this block's staged far records
    if (tid == 0) {
        unsigned n = min(fcnt, (unsigned)FCAP);
        fbase = atomicAdd(counter, n);
    }
    __syncthreads();
    unsigned nst = min(fcnt, (unsigned)FCAP);
    for (unsigned q = tid; q < nst; q += BLK) {
        unsigned gi = fbase + q;
        if (gi < (unsigned)cap) list[gi] = fstage[q];
    }

    // flush: 2x2 box-sum of A, plain exclusive coalesced store to ws planes
    for (int q = tid; q < TW * TH; q += BLK) {
        int oyy = q / TW;
        int oxx = q - oyy * TW;
        int base = (oyy + 1) * AW + (oxx + 1);
        float c  = lc[base] + lc[base - 1] + lc[base - AW] + lc[base - AW - 1];
        float sx = lx[base] + lx[base - 1] + lx[base - AW] + lx[base - AW - 1];
        float sy = ly[base] + ly[base - 1] + ly[base - AW] + ly[base - AW - 1];
        int g = (y0 + oyy) * W + x0 + oxx;
        cm[g]  = c;
        sxm[g] = sx;
        sym[g] = sy;
    }
}

__global__ void scatter_far(const float4* __restrict__ list,
                            const unsigned* __restrict__ counter, int cap,
                            float* __restrict__ cnt_all, float* __restrict__ sx_all,
                            float* __restrict__ sy_all, int HWp, int W, int H)
{
    unsigned n = min(counter[0], (unsigned)cap);
    for (unsigned i = blockIdx.x * blockDim.x + threadIdx.x; i < n;
         i += gridDim.x * blockDim.x) {
        float4 e = list[i];
        unsigned key = __float_as_uint(e.x);
        int x = key & 2047u;
        int y = (key >> 11) & 2047u;
        int b = key >> 22;
        int ixR = min(x + 1, W - 1);
        int iyB = min(y + 1, H - 1);
        size_t base = (size_t)b * HWp;
        int i00 = y * W + x,   i01 = y * W + ixR;
        int i10 = iyB * W + x, i11 = iyB * W + ixR;
        atomicAdd(&cnt_all[base + i00], e.y);
        atomicAdd(&cnt_all[base + i01], e.y);
        atomicAdd(&cnt_all[base + i10], e.y);
        atomicAdd(&cnt_all[base + i11], e.y);
        atomicAdd(&sx_all[base + i00], e.z);
        atomicAdd(&sx_all[base + i01], e.z);
        atomicAdd(&sx_all[base + i10], e.z);
        atomicAdd(&sx_all[base + i11], e.z);
        atomicAdd(&sy_all[base + i00], e.w);
        atomicAdd(&sy_all[base + i01], e.w);
        atomicAdd(&sy_all[base + i10], e.w);
        atomicAdd(&sy_all[base + i11], e.w);
    }
}

// fused normalize + hole-fill, float4-vectorized (4 px/thread)
__global__ void norm_fill(const float* __restrict__ cnt_all,
                          const float* __restrict__ sx_all,
                          const float* __restrict__ sy_all,
                          float* __restrict__ out,
                          int B, int H, int W)
{
    int HWp = H * W;
    int t = blockIdx.x * blockDim.x + threadIdx.x;
    int i4 = t * 4;
    if (i4 >= B * HWp) return;
    int b = i4 / HWp;
    int r = i4 - b * HWp;          // HWp % 4 == 0, so all 4 px in same batch
    const float* cb  = cnt_all + (size_t)b * HWp;
    const float* sxb = sx_all + (size_t)b * HWp;
    const float* syb = sy_all + (size_t)b * HWp;
    float4 c4 = *(const float4*)(cb + r);
    float4 x4 = *(const float4*)(sxb + r);
    float4 y4 = *(const float4*)(syb + r);
    float* cp = (float*)&c4;
    float* xp = (float*)&x4;
    float* yp = (float*)&y4;
    float rx[4], ry[4];
    #pragma unroll
    for (int j = 0; j < 4; ++j) {
        float c = cp[j];
        if (c > 0.0f) {
            rx[j] = xp[j] / c;
            ry[j] = yp[j] / c;
        } else {
            int rr = r + j;
            int y = rr / W;
            int x = rr - y * W;
            float nx = 0.0f, ny = 0.0f;
            int den = 0;
            for (int xx = x - 1; xx >= 0; --xx) {
                int q = y * W + xx; float cq = cb[q];
                if (cq > 0.0f) { nx += sxb[q] / cq; ny += syb[q] / cq; ++den; break; }
            }
            for (int xx = x + 1; xx < W; ++xx) {
                int q = y * W + xx; float cq = cb[q];
                if (cq > 0.0f) { nx += sxb[q] / cq; ny += syb[q] / cq; ++den; break; }
            }
            for (int yy = y - 1; yy >= 0; --yy) {
                int q = yy * W + x; float cq = cb[q];
                if (cq > 0.0f) { nx += sxb[q] / cq; ny += syb[q] / cq; ++den; break; }
            }
            for (int yy = y + 1; yy < H; ++yy) {
                int q = yy * W + x; float cq = cb[q];
                if (cq > 0.0f) { nx += sxb[q] / cq; ny += syb[q] / cq; ++den; break; }
            }
            if (den > 0) { float fd = (float)den; rx[j] = nx / fd; ry[j] = ny / fd; }
            else         { rx[j] = 0.0f; ry[j] = 0.0f; }
        }
    }
    float* ob = out + (size_t)b * 2 * HWp;
    *(float4*)(ob + r)       = make_float4(rx[0], rx[1], rx[2], rx[3]);
    *(float4*)(ob + HWp + r) = make_float4(ry[0], ry[1], ry[2], ry[3]);
}

// fallback (ws too small / shape mismatch): global atomics into ws planes
__global__ void splat_naive_ws(const float* __restrict__ flow,
                               const float* __restrict__ depth,
                               float* __restrict__ cnt_all,
                               float* __restrict__ sx_all,
                               float* __restrict__ sy_all,
                               int B, int H, int W)
{
    int i = blockIdx.x * blockDim.x + threadIdx.x;
    int HWp = H * W;
    if (i >= B * HWp) return;
    int b = i / HWp;
    int p = i - b * HWp;
    int y = p / W;
    int x = p - y * W;
    const float* fb = flow + (size_t)b * 2 * HWp;
    float fx = fb[p], fy = fb[HWp + p];
    float x2 = (float)x + fx, y2 = (float)y + fy;
    if (!(x2 >= 0.0f && y2 >= 0.0f && x2 <= (float)(W - 1) && y2 <= (float)(H - 1)))
        return;
    float w = depth[i];
    int ixL = min((int)x2, W - 1);
    int iyT = min((int)y2, H - 1);
    int ixR = min(ixL + 1, W - 1);
    int iyB = min(iyT + 1, H - 1);
    float ax = -fx * w, ay = -fy * w;
    size_t base = (size_t)b * HWp;
    int idx[4] = {iyT * W + ixL, iyT * W + ixR, iyB * W + ixL, iyB * W + ixR};
    #pragma unroll
    for (int c = 0; c < 4; ++c) {
        atomicAdd(&cnt_all[base + idx[c]], w);
        atomicAdd(&sx_all[base + idx[c]], ax);
        atomicAdd(&sy_all[base + idx[c]], ay);
    }
}

extern "C" void kernel_launch(void* const* d_in, const int* in_sizes, int n_in,
                              void* d_out, int out_size, void* d_ws, size_t ws_size,
                              hipStream_t stream) {
    const float* flow  = (const float*)d_in[0];   // (B,2,H,W)
    const float* depth = (const float*)d_in[1];   // (B,1,H,W)
    float* out = (float*)d_out;                   // (B,2,H,W)

    const int H = 1080, W = 1920;
    const int HWp = H * W;
    const int B = in_sizes[1] / HWp;
    const size_t plane = (size_t)B * HWp;

    // ws layout: [cnt plane][sx plane][sy plane][256B counter][far list]
    float* cnt_all = (float*)d_ws;
    float* sx_all  = cnt_all + plane;
    float* sy_all  = cnt_all + 2 * plane;
    unsigned* counter = (unsigned*)(cnt_all + 3 * plane);
    float4* list = (float4*)((char*)counter + 256);
    size_t head = 3 * plane * sizeof(float) + 256;
    long long cap_ll = (ws_size > head) ? (long long)((ws_size - head) / 16) : 0;
    if (cap_ll > 4000000LL) cap_ll = 4000000LL;
    int cap = (int)cap_ll;

    int blocks = (int)((plane + 255) / 256);
    bool tiled = (cap >= 200000) && (W % TW == 0) && (H % TH == 0);

    if (tiled) {
        hipMemsetAsync(counter, 0, 256, stream);   // only the counter
        dim3 grid(W / TW, H / TH, B);              // 24 x 18 x 4
        splat_box<<<grid, BLK, 0, stream>>>(flow, depth, cnt_all, sx_all, sy_all,
                                            counter, list, cap, B, H, W);
        scatter_far<<<128, 256, 0, stream>>>(list, counter, cap,
                                             cnt_all, sx_all, sy_all, HWp, W, H);
        int vblocks = (int)((plane / 4 + 255) / 256);
        norm_fill<<<vblocks, 256, 0, stream>>>(cnt_all, sx_all, sy_all, out, B, H, W);
    } else if (ws_size >= 3 * plane * sizeof(float)) {
        hipMemsetAsync(d_ws, 0, 3 * plane * sizeof(float), stream);
        splat_naive_ws<<<blocks, 256, 0, stream>>>(flow, depth,
                                                   cnt_all, sx_all, sy_all,
                                                   B, H, W);
        int vblocks = (int)((plane / 4 + 255) / 256);
        norm_fill<<<vblocks, 256, 0, stream>>>(cnt_all, sx_all, sy_all, out, B, H, W);
    }
}

// Round 11
// 205.709 us; speedup vs baseline: 2.2894x; 1.3748x over previous
//
#include <hip/hip_runtime.h>

// DepthFlowProjectionModule — B=4, H=1080, W=1920, fp32.
// Round 11 = Round 10 resubmit (container unresponsive; no result obtained).
// Cut LDS atomics 3 -> 2 per pixel. Measured DS-pipe law:
// ~5ns/lane-atomic (R5 100M=550us, R6/R9 25M=178us) => ~125us of splat is
// the DS RMW pipe. Pack (sx,sy) into ONE u64 LDS atomic as bias-positive
// fixed point (20 frac bits): field = rn(m*(32 -/+ f)*w*2^20); bias debias
// is EXACT via cnt at flush: sx = hi*2^-20 - 32*cnt. Near path guarantees
// |fx|<24, |fy|<26 so fields are positive; wrap needs >=70 deposits/cell
// (target density ~Poisson(1-2): never). cnt stays exact f32 atomic.
// Everything else = Round 9 (block-aggregated far list, scatter_far,
// float4 norm_fill).

#define TW 80
#define TH 60
#define AW 81             // A-plane cols  (x0-1 .. x0+TW-1)
#define AH 61             // A-plane rows  (y0-1 .. y0+TH-1)
#define APIX (AW * AH)    // 4941 cells; u64 plane + f32 plane = 59292 B LDS
#define EW 128            // read region: gx in [x0-24, x0+103]
#define EH 112            // read region: gy in [y0-26, y0+85]; EW*EH = 14*1024
#define RX 24
#define RY 26
#define DXLO (-24)
#define DXHI 23
#define DYLO (-26)
#define DYHI 25
#define BLK 1024
#define FCAP 256          // LDS far-record staging (expected ~26/block)
#define FPSCALE 1048576.0f      // 2^20
#define FPINV   9.5367431640625e-7f  // 2^-20

__global__ __launch_bounds__(BLK, 2) void splat_box(
    const float* __restrict__ flow, const float* __restrict__ depth,
    float* __restrict__ cnt_all, float* __restrict__ sx_all,
    float* __restrict__ sy_all,
    unsigned* __restrict__ counter, float4* __restrict__ list, int cap,
    int B, int H, int W)
{
    __shared__ unsigned long long lpk[APIX];   // (sx_fixed<<32)|sy_fixed, biased
    __shared__ float lcf[APIX];                // cnt = sum of m*w
    __shared__ float4 fstage[FCAP];
    __shared__ unsigned fcnt, fbase;

    int tid = threadIdx.x;
    for (int q = tid; q < APIX; q += BLK) { lpk[q] = 0ULL; lcf[q] = 0.0f; }
    if (tid == 0) fcnt = 0;
    __syncthreads();

    int x0 = blockIdx.x * TW;
    int y0 = blockIdx.y * TH;
    int b  = blockIdx.z;
    int HWp = H * W;
    const float* fb = flow + (size_t)b * 2 * HWp;
    const float* db = depth + (size_t)b * HWp;
    float* cm  = cnt_all + (size_t)b * HWp;
    float* sxm = sx_all + (size_t)b * HWp;
    float* sym = sy_all + (size_t)b * HWp;

    #pragma unroll
    for (int k = 0; k < (EW * EH) / BLK; ++k) {   // 14 exact iterations
        int q = tid + k * BLK;
        int ex = q & (EW - 1);
        int ey = q >> 7;
        int gx = x0 - RX + ex;
        int gy = y0 - RY + ey;
        if ((unsigned)gx >= (unsigned)W || (unsigned)gy >= (unsigned)H) continue;
        int p = gy * W + gx;
        float fx = fb[p], fy = fb[HWp + p];
        float x2 = (float)gx + fx;
        float y2 = (float)gy + fy;
        if (!(x2 >= 0.0f && y2 >= 0.0f && x2 <= (float)(W - 1) && y2 <= (float)(H - 1)))
            continue;
        float w = db[p];
        int ixL = min((int)x2, W - 1);   // x2>=0 -> trunc == floor == jnp astype+clip
        int iyT = min((int)y2, H - 1);
        int dx = ixL - gx;
        int dy = iyT - gy;
        bool near = (dx >= DXLO) & (dx <= DXHI) & (dy >= DYLO) & (dy <= DYHI);
        if (near) {
            int ax = ixL - (x0 - 1);
            int ay = iyT - (y0 - 1);
            if ((unsigned)ax < (unsigned)AW && (unsigned)ay < (unsigned)AH) {
                float m = ((ixL == W - 1) ? 2.0f : 1.0f) *
                          ((iyT == H - 1) ? 2.0f : 1.0f);
                float mw = m * w;
                // biased-positive fixed point; near => |fx|<24, |fy|<26 < 32
                unsigned ux = __float2uint_rn((32.0f - fx) * mw * FPSCALE);
                unsigned uy = __float2uint_rn((32.0f - fy) * mw * FPSCALE);
                int l = ay * AW + ax;
                atomicAdd(&lpk[l], ((unsigned long long)ux << 32) | uy);
                atomicAdd(&lcf[l], mw);
            }
        } else if (((unsigned)(gx - x0) < (unsigned)TW) &&
                   ((unsigned)(gy - y0) < (unsigned)TH)) {
            // far tail: stage in LDS (per-CU atomic); global fallback if full
            unsigned key = (unsigned)ixL | ((unsigned)iyT << 11) | ((unsigned)b << 22);
            float4 rec = make_float4(__uint_as_float(key), w, -fx * w, -fy * w);
            unsigned li = atomicAdd(&fcnt, 1u);
            if (li < FCAP) {
                fstage[li] = rec;
            } else {
                unsigned gi = atomicAdd(counter, 1u);
                if (gi < (unsigned)cap) list[gi] = rec;
            }
        }
    }
    __syncthreads();

    // reserve one contiguous chunk for this block's staged far records
    if (tid == 0) {
        unsigned n = min(fcnt, (unsigned)FCAP);
        fbase = atomicAdd(counter, n);
    }
    __syncthreads();
    unsigned nst = min(fcnt, (unsigned)FCAP);
    for (unsigned q = tid; q < nst; q += BLK) {
        unsigned gi = fbase + q;
        if (gi < (unsigned)cap) list[gi] = fstage[q];
    }

    // flush: per-cell debias (exact via cnt), then 2x2 box-sum; exclusive store
    for (int q = tid; q < TW * TH; q += BLK) {
        int oyy = q / TW;
        int oxx = q - oyy * TW;
        int base = (oyy + 1) * AW + (oxx + 1);
        float c = 0.0f, sx = 0.0f, sy = 0.0f;
        #pragma unroll
        for (int j = 0; j < 4; ++j) {
            int l = base - (j & 1) - (j >> 1) * AW;
            unsigned long long pk = lpk[l];
            float cc = lcf[l];
            float bias = 32.0f * cc;
            c  += cc;
            sx += (float)(unsigned)(pk >> 32) * FPINV - bias;
            sy += (float)(unsigned)(pk & 0xFFFFFFFFULL) * FPINV - bias;
        }
        int g = (y0 + oyy) * W + x0 + oxx;
        cm[g]  = c;
        sxm[g] = sx;
        sym[g] = sy;
    }
}

__global__ void scatter_far(const float4* __restrict__ list,
                            const unsigned* __restrict__ counter, int cap,
                            float* __restrict__ cnt_all, float* __restrict__ sx_all,
                            float* __restrict__ sy_all, int HWp, int W, int H)
{
    unsigned n = min(counter[0], (unsigned)cap);
    for (unsigned i = blockIdx.x * blockDim.x + threadIdx.x; i < n;
         i += gridDim.x * blockDim.x) {
        float4 e = list[i];
        unsigned key = __float_as_uint(e.x);
        int x = key & 2047u;
        int y = (key >> 11) & 2047u;
        int b = key >> 22;
        int ixR = min(x + 1, W - 1);
        int iyB = min(y + 1, H - 1);
        size_t base = (size_t)b * HWp;
        int i00 = y * W + x,   i01 = y * W + ixR;
        int i10 = iyB * W + x, i11 = iyB * W + ixR;
        atomicAdd(&cnt_all[base + i00], e.y);
        atomicAdd(&cnt_all[base + i01], e.y);
        atomicAdd(&cnt_all[base + i10], e.y);
        atomicAdd(&cnt_all[base + i11], e.y);
        atomicAdd(&sx_all[base + i00], e.z);
        atomicAdd(&sx_all[base + i01], e.z);
        atomicAdd(&sx_all[base + i10], e.z);
        atomicAdd(&sx_all[base + i11], e.z);
        atomicAdd(&sy_all[base + i00], e.w);
        atomicAdd(&sy_all[base + i01], e.w);
        atomicAdd(&sy_all[base + i10], e.w);
        atomicAdd(&sy_all[base + i11], e.w);
    }
}

// fused normalize + hole-fill, float4-vectorized (4 px/thread)
__global__ void norm_fill(const float* __restrict__ cnt_all,
                          const float* __restrict__ sx_all,
                          const float* __restrict__ sy_all,
                          float* __restrict__ out,
                          int B, int H, int W)
{
    int HWp = H * W;
    int t = blockIdx.x * blockDim.x + threadIdx.x;
    int i4 = t * 4;
    if (i4 >= B * HWp) return;
    int b = i4 / HWp;
    int r = i4 - b * HWp;          // HWp % 4 == 0, so all 4 px in same batch
    const float* cb  = cnt_all + (size_t)b * HWp;
    const float* sxb = sx_all + (size_t)b * HWp;
    const float* syb = sy_all + (size_t)b * HWp;
    float4 c4 = *(const float4*)(cb + r);
    float4 x4 = *(const float4*)(sxb + r);
    float4 y4 = *(const float4*)(syb + r);
    float* cp = (float*)&c4;
    float* xp = (float*)&x4;
    float* yp = (float*)&y4;
    float rx[4], ry[4];
    #pragma unroll
    for (int j = 0; j < 4; ++j) {
        float c = cp[j];
        if (c > 0.0f) {
            rx[j] = xp[j] / c;
            ry[j] = yp[j] / c;
        } else {
            int rr = r + j;
            int y = rr / W;
            int x = rr - y * W;
            float nx = 0.0f, ny = 0.0f;
            int den = 0;
            for (int xx = x - 1; xx >= 0; --xx) {
                int q = y * W + xx; float cq = cb[q];
                if (cq > 0.0f) { nx += sxb[q] / cq; ny += syb[q] / cq; ++den; break; }
            }
            for (int xx = x + 1; xx < W; ++xx) {
                int q = y * W + xx; float cq = cb[q];
                if (cq > 0.0f) { nx += sxb[q] / cq; ny += syb[q] / cq; ++den; break; }
            }
            for (int yy = y - 1; yy >= 0; --yy) {
                int q = yy * W + x; float cq = cb[q];
                if (cq > 0.0f) { nx += sxb[q] / cq; ny += syb[q] / cq; ++den; break; }
            }
            for (int yy = y + 1; yy < H; ++yy) {
                int q = yy * W + x; float cq = cb[q];
                if (cq > 0.0f) { nx += sxb[q] / cq; ny += syb[q] / cq; ++den; break; }
            }
            if (den > 0) { float fd = (float)den; rx[j] = nx / fd; ry[j] = ny / fd; }
            else         { rx[j] = 0.0f; ry[j] = 0.0f; }
        }
    }
    float* ob = out + (size_t)b * 2 * HWp;
    *(float4*)(ob + r)       = make_float4(rx[0], rx[1], rx[2], rx[3]);
    *(float4*)(ob + HWp + r) = make_float4(ry[0], ry[1], ry[2], ry[3]);
}

// fallback (ws too small / shape mismatch): global atomics into ws planes
__global__ void splat_naive_ws(const float* __restrict__ flow,
                               const float* __restrict__ depth,
                               float* __restrict__ cnt_all,
                               float* __restrict__ sx_all,
                               float* __restrict__ sy_all,
                               int B, int H, int W)
{
    int i = blockIdx.x * blockDim.x + threadIdx.x;
    int HWp = H * W;
    if (i >= B * HWp) return;
    int b = i / HWp;
    int p = i - b * HWp;
    int y = p / W;
    int x = p - y * W;
    const float* fb = flow + (size_t)b * 2 * HWp;
    float fx = fb[p], fy = fb[HWp + p];
    float x2 = (float)x + fx, y2 = (float)y + fy;
    if (!(x2 >= 0.0f && y2 >= 0.0f && x2 <= (float)(W - 1) && y2 <= (float)(H - 1)))
        return;
    float w = depth[i];
    int ixL = min((int)x2, W - 1);
    int iyT = min((int)y2, H - 1);
    int ixR = min(ixL + 1, W - 1);
    int iyB = min(iyT + 1, H - 1);
    float ax = -fx * w, ay = -fy * w;
    size_t base = (size_t)b * HWp;
    int idx[4] = {iyT * W + ixL, iyT * W + ixR, iyB * W + ixL, iyB * W + ixR};
    #pragma unroll
    for (int c = 0; c < 4; ++c) {
        atomicAdd(&cnt_all[base + idx[c]], w);
        atomicAdd(&sx_all[base + idx[c]], ax);
        atomicAdd(&sy_all[base + idx[c]], ay);
    }
}

extern "C" void kernel_launch(void* const* d_in, const int* in_sizes, int n_in,
                              void* d_out, int out_size, void* d_ws, size_t ws_size,
                              hipStream_t stream) {
    const float* flow  = (const float*)d_in[0];   // (B,2,H,W)
    const float* depth = (const float*)d_in[1];   // (B,1,H,W)
    float* out = (float*)d_out;                   // (B,2,H,W)

    const int H = 1080, W = 1920;
    const int HWp = H * W;
    const int B = in_sizes[1] / HWp;
    const size_t plane = (size_t)B * HWp;

    // ws layout: [cnt plane][sx plane][sy plane][256B counter][far list]
    float* cnt_all = (float*)d_ws;
    float* sx_all  = cnt_all + plane;
    float* sy_all  = cnt_all + 2 * plane;
    unsigned* counter = (unsigned*)(cnt_all + 3 * plane);
    float4* list = (float4*)((char*)counter + 256);
    size_t head = 3 * plane * sizeof(float) + 256;
    long long cap_ll = (ws_size > head) ? (long long)((ws_size - head) / 16) : 0;
    if (cap_ll > 4000000LL) cap_ll = 4000000LL;
    int cap = (int)cap_ll;

    int blocks = (int)((plane + 255) / 256);
    bool tiled = (cap >= 200000) && (W % TW == 0) && (H % TH == 0);

    if (tiled) {
        hipMemsetAsync(counter, 0, 256, stream);   // only the counter
        dim3 grid(W / TW, H / TH, B);              // 24 x 18 x 4
        splat_box<<<grid, BLK, 0, stream>>>(flow, depth, cnt_all, sx_all, sy_all,
                                            counter, list, cap, B, H, W);
        scatter_far<<<256, 256, 0, stream>>>(list, counter, cap,
                                             cnt_all, sx_all, sy_all, HWp, W, H);
        int vblocks = (int)((plane / 4 + 255) / 256);
        norm_fill<<<vblocks, 256, 0, stream>>>(cnt_all, sx_all, sy_all, out, B, H, W);
    } else if (ws_size >= 3 * plane * sizeof(float)) {
        hipMemsetAsync(d_ws, 0, 3 * plane * sizeof(float), stream);
        splat_naive_ws<<<blocks, 256, 0, stream>>>(flow, depth,
                                                   cnt_all, sx_all, sy_all,
                                                   B, H, W);
        int vblocks = (int)((plane / 4 + 255) / 256);
        norm_fill<<<vblocks, 256, 0, stream>>>(cnt_all, sx_all, sy_all, out, B, H, W);
    }
}

// Round 13
// 198.324 us; speedup vs baseline: 2.3747x; 1.0372x over previous
//
#include <hip/hip_runtime.h>

// DepthFlowProjectionModule — B=4, H=1080, W=1920, fp32.
// Round 13: revert to R11 numerics (PROVEN: u64-packed sx,sy @20 frac bits +
// f32 cnt = 2 LDS atomics/px, absmax 0.125; the 1-op pack of R12 is
// information-theoretically impossible: 3 fields x ~27 bits > 64 given
// w_min=0.001). New: 4-px-per-thread vectorized read loop — 3x float4 loads
// (group alignment exact: W%4==0, x0%4==0, RX%4==0), per-GROUP bounds checks,
// amortized address math. Attacks the ~42us non-atomic base of splat's 108us.
// Far list, scatter_far, float4 norm_fill unchanged from R11.

#define TW 80
#define TH 60
#define AW 81             // A-plane cols  (x0-1 .. x0+TW-1)
#define AH 61             // A-plane rows  (y0-1 .. y0+TH-1)
#define APIX (AW * AH)    // 4941 cells; u64 plane + f32 plane = 59292 B LDS
#define EW 128            // read region: gx in [x0-24, x0+103]
#define EH 112            // read region: gy in [y0-26, y0+85]
#define RX 24
#define RY 26
#define DXLO (-24)
#define DXHI 23
#define DYLO (-26)
#define DYHI 25
#define BLK 1024
#define FCAP 256          // LDS far-record staging (expected ~26/block)
#define FPSCALE 1048576.0f      // 2^20
#define FPINV   9.5367431640625e-7f  // 2^-20

__global__ __launch_bounds__(BLK, 2) void splat_box(
    const float* __restrict__ flow, const float* __restrict__ depth,
    float* __restrict__ cnt_all, float* __restrict__ sx_all,
    float* __restrict__ sy_all,
    unsigned* __restrict__ counter, float4* __restrict__ list, int cap,
    int B, int H, int W)
{
    __shared__ unsigned long long lpk[APIX];   // (sx_fixed<<32)|sy_fixed, biased
    __shared__ float lcf[APIX];                // cnt = sum of m*w
    __shared__ float4 fstage[FCAP];
    __shared__ unsigned fcnt, fbase;

    int tid = threadIdx.x;
    for (int q = tid; q < APIX; q += BLK) { lpk[q] = 0ULL; lcf[q] = 0.0f; }
    if (tid == 0) fcnt = 0;
    __syncthreads();

    int x0 = blockIdx.x * TW;
    int y0 = blockIdx.y * TH;
    int b  = blockIdx.z;
    int HWp = H * W;
    const float* fb = flow + (size_t)b * 2 * HWp;
    const float* db = depth + (size_t)b * HWp;
    float* cm  = cnt_all + (size_t)b * HWp;
    float* sxm = sx_all + (size_t)b * HWp;
    float* sym = sy_all + (size_t)b * HWp;

    // 4 px per thread: 32 col-groups x 32 rows per k-iteration
    int cg = tid & 31;            // column group (4 px each)
    int rr = tid >> 5;            // row within the 32-row slab
    int gx0 = x0 - RX + cg * 4;   // group base col (multiple of 4)
    bool gx_ok = (unsigned)gx0 < (unsigned)W;   // whole group in/out (W%4==0)

    #pragma unroll
    for (int k = 0; k < 4; ++k) {
        int ey = k * 32 + rr;
        if (ey >= EH) continue;                 // only k=3, rr>=16
        int gy = y0 - RY + ey;
        if (!gx_ok || (unsigned)gy >= (unsigned)H) continue;
        int p = gy * W + gx0;
        float4 fx4 = *(const float4*)(fb + p);
        float4 fy4 = *(const float4*)(fb + HWp + p);
        float4 w4  = *(const float4*)(db + p);
        const float* fxp = (const float*)&fx4;
        const float* fyp = (const float*)&fy4;
        const float* wp  = (const float*)&w4;
        #pragma unroll
        for (int j = 0; j < 4; ++j) {
            int gx = gx0 + j;
            float fx = fxp[j], fy = fyp[j];
            float x2 = (float)gx + fx;
            float y2 = (float)gy + fy;
            if (!(x2 >= 0.0f && y2 >= 0.0f &&
                  x2 <= (float)(W - 1) && y2 <= (float)(H - 1)))
                continue;
            float w = wp[j];
            int ixL = min((int)x2, W - 1);  // x2>=0 -> trunc == floor == astype+clip
            int iyT = min((int)y2, H - 1);
            int dx = ixL - gx;
            int dy = iyT - gy;
            bool near = (dx >= DXLO) & (dx <= DXHI) & (dy >= DYLO) & (dy <= DYHI);
            if (near) {
                int ax = ixL - (x0 - 1);
                int ay = iyT - (y0 - 1);
                if ((unsigned)ax < (unsigned)AW && (unsigned)ay < (unsigned)AH) {
                    float m = ((ixL == W - 1) ? 2.0f : 1.0f) *
                              ((iyT == H - 1) ? 2.0f : 1.0f);
                    float mw = m * w;
                    // biased-positive fixed point; near => |fx|<24, |fy|<26 < 32
                    unsigned ux = __float2uint_rn((32.0f - fx) * mw * FPSCALE);
                    unsigned uy = __float2uint_rn((32.0f - fy) * mw * FPSCALE);
                    int l = ay * AW + ax;
                    atomicAdd(&lpk[l], ((unsigned long long)ux << 32) | uy);
                    atomicAdd(&lcf[l], mw);
                }
            } else if (((unsigned)(gx - x0) < (unsigned)TW) &&
                       ((unsigned)(gy - y0) < (unsigned)TH)) {
                // far tail: stage in LDS (per-CU atomic); global fallback if full
                unsigned key = (unsigned)ixL | ((unsigned)iyT << 11) |
                               ((unsigned)b << 22);
                float4 rec = make_float4(__uint_as_float(key), w, -fx * w, -fy * w);
                unsigned li = atomicAdd(&fcnt, 1u);
                if (li < FCAP) {
                    fstage[li] = rec;
                } else {
                    unsigned gi = atomicAdd(counter, 1u);
                    if (gi < (unsigned)cap) list[gi] = rec;
                }
            }
        }
    }
    __syncthreads();

    // reserve one contiguous chunk for this block's staged far records
    if (tid == 0) {
        unsigned n = min(fcnt, (unsigned)FCAP);
        fbase = atomicAdd(counter, n);
    }
    __syncthreads();
    unsigned nst = min(fcnt, (unsigned)FCAP);
    for (unsigned q = tid; q < nst; q += BLK) {
        unsigned gi = fbase + q;
        if (gi < (unsigned)cap) list[gi] = fstage[q];
    }

    // flush: per-cell debias (exact via cnt), then 2x2 box-sum; exclusive store
    for (int q = tid; q < TW * TH; q += BLK) {
        int oyy = q / TW;
        int oxx = q - oyy * TW;
        int base = (oyy + 1) * AW + (oxx + 1);
        float c = 0.0f, sx = 0.0f, sy = 0.0f;
        #pragma unroll
        for (int j = 0; j < 4; ++j) {
            int l = base - (j & 1) - (j >> 1) * AW;
            unsigned long long pk = lpk[l];
            float cc = lcf[l];
            float bias = 32.0f * cc;
            c  += cc;
            sx += (float)(unsigned)(pk >> 32) * FPINV - bias;
            sy += (float)(unsigned)(pk & 0xFFFFFFFFULL) * FPINV - bias;
        }
        int g = (y0 + oyy) * W + x0 + oxx;
        cm[g]  = c;
        sxm[g] = sx;
        sym[g] = sy;
    }
}

__global__ void scatter_far(const float4* __restrict__ list,
                            const unsigned* __restrict__ counter, int cap,
                            float* __restrict__ cnt_all, float* __restrict__ sx_all,
                            float* __restrict__ sy_all, int HWp, int W, int H)
{
    unsigned n = min(counter[0], (unsigned)cap);
    for (unsigned i = blockIdx.x * blockDim.x + threadIdx.x; i < n;
         i += gridDim.x * blockDim.x) {
        float4 e = list[i];
        unsigned key = __float_as_uint(e.x);
        int x = key & 2047u;
        int y = (key >> 11) & 2047u;
        int b = key >> 22;
        int ixR = min(x + 1, W - 1);
        int iyB = min(y + 1, H - 1);
        size_t base = (size_t)b * HWp;
        int i00 = y * W + x,   i01 = y * W + ixR;
        int i10 = iyB * W + x, i11 = iyB * W + ixR;
        atomicAdd(&cnt_all[base + i00], e.y);
        atomicAdd(&cnt_all[base + i01], e.y);
        atomicAdd(&cnt_all[base + i10], e.y);
        atomicAdd(&cnt_all[base + i11], e.y);
        atomicAdd(&sx_all[base + i00], e.z);
        atomicAdd(&sx_all[base + i01], e.z);
        atomicAdd(&sx_all[base + i10], e.z);
        atomicAdd(&sx_all[base + i11], e.z);
        atomicAdd(&sy_all[base + i00], e.w);
        atomicAdd(&sy_all[base + i01], e.w);
        atomicAdd(&sy_all[base + i10], e.w);
        atomicAdd(&sy_all[base + i11], e.w);
    }
}

// fused normalize + hole-fill, float4-vectorized (4 px/thread)
__global__ void norm_fill(const float* __restrict__ cnt_all,
                          const float* __restrict__ sx_all,
                          const float* __restrict__ sy_all,
                          float* __restrict__ out,
                          int B, int H, int W)
{
    int HWp = H * W;
    int t = blockIdx.x * blockDim.x + threadIdx.x;
    int i4 = t * 4;
    if (i4 >= B * HWp) return;
    int b = i4 / HWp;
    int r = i4 - b * HWp;          // HWp % 4 == 0, so all 4 px in same batch
    const float* cb  = cnt_all + (size_t)b * HWp;
    const float* sxb = sx_all + (size_t)b * HWp;
    const float* syb = sy_all + (size_t)b * HWp;
    float4 c4 = *(const float4*)(cb + r);
    float4 x4 = *(const float4*)(sxb + r);
    float4 y4 = *(const float4*)(syb + r);
    float* cp = (float*)&c4;
    float* xp = (float*)&x4;
    float* yp = (float*)&y4;
    float rx[4], ry[4];
    #pragma unroll
    for (int j = 0; j < 4; ++j) {
        float c = cp[j];
        if (c > 0.0f) {
            rx[j] = xp[j] / c;
            ry[j] = yp[j] / c;
        } else {
            int rr = r + j;
            int y = rr / W;
            int x = rr - y * W;
            float nx = 0.0f, ny = 0.0f;
            int den = 0;
            for (int xx = x - 1; xx >= 0; --xx) {
                int q = y * W + xx; float cq = cb[q];
                if (cq > 0.0f) { nx += sxb[q] / cq; ny += syb[q] / cq; ++den; break; }
            }
            for (int xx = x + 1; xx < W; ++xx) {
                int q = y * W + xx; float cq = cb[q];
                if (cq > 0.0f) { nx += sxb[q] / cq; ny += syb[q] / cq; ++den; break; }
            }
            for (int yy = y - 1; yy >= 0; --yy) {
                int q = yy * W + x; float cq = cb[q];
                if (cq > 0.0f) { nx += sxb[q] / cq; ny += syb[q] / cq; ++den; break; }
            }
            for (int yy = y + 1; yy < H; ++yy) {
                int q = yy * W + x; float cq = cb[q];
                if (cq > 0.0f) { nx += sxb[q] / cq; ny += syb[q] / cq; ++den; break; }
            }
            if (den > 0) { float fd = (float)den; rx[j] = nx / fd; ry[j] = ny / fd; }
            else         { rx[j] = 0.0f; ry[j] = 0.0f; }
        }
    }
    float* ob = out + (size_t)b * 2 * HWp;
    *(float4*)(ob + r)       = make_float4(rx[0], rx[1], rx[2], rx[3]);
    *(float4*)(ob + HWp + r) = make_float4(ry[0], ry[1], ry[2], ry[3]);
}

// fallback (ws too small / shape mismatch): global atomics into ws planes
__global__ void splat_naive_ws(const float* __restrict__ flow,
                               const float* __restrict__ depth,
                               float* __restrict__ cnt_all,
                               float* __restrict__ sx_all,
                               float* __restrict__ sy_all,
                               int B, int H, int W)
{
    int i = blockIdx.x * blockDim.x + threadIdx.x;
    int HWp = H * W;
    if (i >= B * HWp) return;
    int b = i / HWp;
    int p = i - b * HWp;
    int y = p / W;
    int x = p - y * W;
    const float* fb = flow + (size_t)b * 2 * HWp;
    float fx = fb[p], fy = fb[HWp + p];
    float x2 = (float)x + fx, y2 = (float)y + fy;
    if (!(x2 >= 0.0f && y2 >= 0.0f && x2 <= (float)(W - 1) && y2 <= (float)(H - 1)))
        return;
    float w = depth[i];
    int ixL = min((int)x2, W - 1);
    int iyT = min((int)y2, H - 1);
    int ixR = min(ixL + 1, W - 1);
    int iyB = min(iyT + 1, H - 1);
    float ax = -fx * w, ay = -fy * w;
    size_t base = (size_t)b * HWp;
    int idx[4] = {iyT * W + ixL, iyT * W + ixR, iyB * W + ixL, iyB * W + ixR};
    #pragma unroll
    for (int c = 0; c < 4; ++c) {
        atomicAdd(&cnt_all[base + idx[c]], w);
        atomicAdd(&sx_all[base + idx[c]], ax);
        atomicAdd(&sy_all[base + idx[c]], ay);
    }
}

extern "C" void kernel_launch(void* const* d_in, const int* in_sizes, int n_in,
                              void* d_out, int out_size, void* d_ws, size_t ws_size,
                              hipStream_t stream) {
    const float* flow  = (const float*)d_in[0];   // (B,2,H,W)
    const float* depth = (const float*)d_in[1];   // (B,1,H,W)
    float* out = (float*)d_out;                   // (B,2,H,W)

    const int H = 1080, W = 1920;
    const int HWp = H * W;
    const int B = in_sizes[1] / HWp;
    const size_t plane = (size_t)B * HWp;

    // ws layout: [cnt plane][sx plane][sy plane][256B counter][far list]
    float* cnt_all = (float*)d_ws;
    float* sx_all  = cnt_all + plane;
    float* sy_all  = cnt_all + 2 * plane;
    unsigned* counter = (unsigned*)(cnt_all + 3 * plane);
    float4* list = (float4*)((char*)counter + 256);
    size_t head = 3 * plane * sizeof(float) + 256;
    long long cap_ll = (ws_size > head) ? (long long)((ws_size - head) / 16) : 0;
    if (cap_ll > 4000000LL) cap_ll = 4000000LL;
    int cap = (int)cap_ll;

    int blocks = (int)((plane + 255) / 256);
    bool tiled = (cap >= 200000) && (W % TW == 0) && (H % TH == 0) && (W % 4 == 0);

    if (tiled) {
        hipMemsetAsync(counter, 0, 256, stream);   // only the counter
        dim3 grid(W / TW, H / TH, B);              // 24 x 18 x 4
        splat_box<<<grid, BLK, 0, stream>>>(flow, depth, cnt_all, sx_all, sy_all,
                                            counter, list, cap, B, H, W);
        scatter_far<<<256, 256, 0, stream>>>(list, counter, cap,
                                             cnt_all, sx_all, sy_all, HWp, W, H);
        int vblocks = (int)((plane / 4 + 255) / 256);
        norm_fill<<<vblocks, 256, 0, stream>>>(cnt_all, sx_all, sy_all, out, B, H, W);
    } else if (ws_size >= 3 * plane * sizeof(float)) {
        hipMemsetAsync(d_ws, 0, 3 * plane * sizeof(float), stream);
        splat_naive_ws<<<blocks, 256, 0, stream>>>(flow, depth,
                                                   cnt_all, sx_all, sy_all,
                                                   B, H, W);
        int vblocks = (int)((plane / 4 + 255) / 256);
        norm_fill<<<vblocks, 256, 0, stream>>>(cnt_all, sx_all, sy_all, out, B, H, W);
    }
}